// Round 11
// baseline (126.354 us; speedup 1.0000x reference)
//
#include <hip/hip_runtime.h>
#include <hip/hip_bf16.h>
#include <stdint.h>

typedef __bf16 bf16;
typedef bf16 bf16x8 __attribute__((ext_vector_type(8)));
typedef bf16 bf16x4 __attribute__((ext_vector_type(4)));
typedef float f32x4 __attribute__((ext_vector_type(4)));

#define MFMA_16x16x32(a, b, c) __builtin_amdgcn_mfma_f32_16x16x32_bf16((a), (b), (c), 0, 0, 0)

// ---- problem sizes ----
constexpr int B = 16, S = 512, H = 768, NH = 12, DH = 64;
constexpr long NHID = (long)B * S * H;          // 6291456

// ---- workspace layout (bytes) ----
constexpr size_t XB_OFF = 0;
constexpr size_t XB_SZ  = (size_t)NHID * 2;
constexpr size_t PROJ_SZ = (size_t)B * NH * S * DH * 2;  // 12582912
constexpr size_t QB_OFF = XB_OFF + XB_SZ;
constexpr size_t KB_OFF = QB_OFF + PROJ_SZ;
constexpr size_t VB_OFF = KB_OFF + PROJ_SZ;              // V^T: [B,NH,DH,S]
constexpr size_t WS_NEED = VB_OFF + PROJ_SZ;             // ~50 MB

// ---------------- X-only f32 -> bf16 convert ----------------
__global__ void cvt_x(const float* __restrict__ src, bf16* __restrict__ dst) {
  long i = ((long)blockIdx.x * blockDim.x + threadIdx.x) * 8;
  if (i >= NHID) return;
  const float4* sp = reinterpret_cast<const float4*>(src + i);
  float4 a = sp[0], b = sp[1];
  bf16x8 o;
  o[0] = (bf16)a.x; o[1] = (bf16)a.y; o[2] = (bf16)a.z; o[3] = (bf16)a.w;
  o[4] = (bf16)b.x; o[5] = (bf16)b.y; o[6] = (bf16)b.z; o[7] = (bf16)b.w;
  *reinterpret_cast<bf16x8*>(dst + i) = o;
}

// ---------------- projection GEMM (R7 structure + W-f32 direct) ----------------
// 576 blocks = 8 XCD-groups x (2 batches x 2 m-tiles x 18 n-tiles), 512 thr.
// BM=256, BN=128, BK=32, dbuf. A = X bf16 (gload_lds, R7-verified swizzle).
// B = W f32 staged DIRECTLY via gload_lds (no cvt pass for W); f32->bf16 at
// fragment read (2x ds_read_b128 + cvt_pk). B slot s of row holds global
// chunk s^(row&7); read chunk c at slot c^(row&7).
// Q,K written [B,NH,S,DH]; V written TRANSPOSED [B,NH,DH,S].
__global__ __launch_bounds__(512, 2) void proj_gemm(
    const bf16* __restrict__ Xb,
    const float* __restrict__ Wqf, const float* __restrict__ Wkf, const float* __restrict__ Wvf,
    const float* __restrict__ bq, const float* __restrict__ bk, const float* __restrict__ bv,
    const int* __restrict__ eidx,
    bf16* __restrict__ Qb, bf16* __restrict__ Kb, bf16* __restrict__ Vb)
{
  __shared__ __align__(16) bf16  As[2][256 * 32];   // 32 KB
  __shared__ __align__(16) float Bsf[2][128 * 32];  // 32 KB

  // XCD-grouped decode: xcd = blk&7 owns batches {2*xcd, 2*xcd+1}
  const int xcd = blockIdx.x & 7;
  const int bi  = blockIdx.x >> 3;            // 0..71
  const int b   = xcd * 2 + (bi / 36);        // batch
  const int rem = bi % 36;                    // 2 m-tiles x 18 n-tiles
  const int m0  = (rem / 18) * 256;
  const int gy  = rem % 18;
  const int proj = gy / 6;
  const int n0 = (gy % 6) * 128;
  const int e = eidx[b];

  const float* W = (proj == 0 ? Wqf : (proj == 1 ? Wkf : Wvf)) + (size_t)e * H * H;
  const float* bias = (proj == 0 ? bq : (proj == 1 ? bk : bv)) + (size_t)e * H;
  bf16* Out = (proj == 0 ? Qb : (proj == 1 ? Kb : Vb));

  const int tid = threadIdx.x;
  const int lane = tid & 63;
  const int wave = tid >> 6;                  // 0..7
  const int wm = wave >> 1, wn = wave & 1;    // 4 x 64 m, 2 x 64 n
  const int r = lane & 15, lg = lane >> 4;

  const bf16* Abase = Xb + ((size_t)b * S + m0) * H;
  const float* Bbase = W + (size_t)n0 * H;

  // A staging (R7-verified): unit = 16 rows x 32 bf16; 2 units/wave.
  const int srowA = lane >> 2;                           // 0..15
  const int sgA = ((lane & 3) ^ ((lane >> 3) & 3)) * 8;  // bf16 elems
  // B staging (f32): unit = 8 rows x 32 f32; 2 units/wave.
  const int srowB = lane >> 3;                           // 0..7
  const int sgB = ((lane & 7) ^ srowB) * 4;              // f32 elems

  auto stage = [&](int kt, int pb) {
    const int k0 = kt * 32;
#pragma unroll
    for (int i = 0; i < 2; ++i) {
      const int seg = wave * 2 + i;                      // 0..15 (A units)
      const bf16* ga = Abase + (size_t)(seg * 16 + srowA) * H + k0 + sgA;
      __builtin_amdgcn_global_load_lds(
          (const __attribute__((address_space(1))) void*)ga,
          (__attribute__((address_space(3))) void*)(&As[pb][seg * 512]), 16, 0, 0);
    }
#pragma unroll
    for (int i = 0; i < 2; ++i) {
      const int u = wave * 2 + i;                        // 0..15 (B units)
      const float* gb = Bbase + (size_t)(u * 8 + srowB) * H + k0 + sgB;
      __builtin_amdgcn_global_load_lds(
          (const __attribute__((address_space(1))) void*)gb,
          (__attribute__((address_space(3))) void*)(&Bsf[pb][u * 256]), 16, 0, 0);
    }
  };

  f32x4 acc[4][4] = {};

  stage(0, 0);
  __syncthreads();

  const int sz = (r >> 1) & 3;   // A read-side swizzle index

  int buf = 0;
#pragma unroll 1
  for (int kt = 0; kt < 24; ++kt) {
    if (kt < 23) stage(kt + 1, buf ^ 1);   // prefetch flies under this tile's MFMAs

    bf16x8 af[4], bfr[4];
#pragma unroll
    for (int mi = 0; mi < 4; ++mi)
      af[mi] = *reinterpret_cast<const bf16x8*>(
          &As[buf][(wm * 64 + mi * 16 + r) * 32 + ((lg ^ sz) * 8)]);
#pragma unroll
    for (int ni = 0; ni < 4; ++ni) {
      const int row = wn * 64 + ni * 16 + r;
      const int k7 = row & 7;
      f32x4 x0 = *reinterpret_cast<const f32x4*>(&Bsf[buf][row * 32 + (((lg * 2) ^ k7) * 4)]);
      f32x4 x1 = *reinterpret_cast<const f32x4*>(&Bsf[buf][row * 32 + (((lg * 2 + 1) ^ k7) * 4)]);
      bf16x8 o;
      o[0] = (bf16)x0[0]; o[1] = (bf16)x0[1]; o[2] = (bf16)x0[2]; o[3] = (bf16)x0[3];
      o[4] = (bf16)x1[0]; o[5] = (bf16)x1[1]; o[6] = (bf16)x1[2]; o[7] = (bf16)x1[3];
      bfr[ni] = o;
    }
    __builtin_amdgcn_s_setprio(1);
#pragma unroll
    for (int mi = 0; mi < 4; ++mi)
#pragma unroll
      for (int ni = 0; ni < 4; ++ni)
        acc[mi][ni] = MFMA_16x16x32(af[mi], bfr[ni], acc[mi][ni]);
    __builtin_amdgcn_s_setprio(0);

    __syncthreads();   // next tile staged + all waves done with buf
    buf ^= 1;
  }

  // epilogue: bias add, cast bf16
  if (proj != 2) {
    // Q,K: [B,NH,S,DH] scatter
#pragma unroll
    for (int ni = 0; ni < 4; ++ni) {
      const int col = n0 + wn * 64 + ni * 16 + r;
      const int nh = col >> 6, dh = col & 63;
      const float bb = bias[col];
      bf16* orow = Out + ((size_t)b * NH + nh) * S * DH + dh;
#pragma unroll
      for (int mi = 0; mi < 4; ++mi) {
#pragma unroll
        for (int rr = 0; rr < 4; ++rr) {
          const int srow2 = m0 + wm * 64 + mi * 16 + lg * 4 + rr;
          orow[(size_t)srow2 * DH] = (bf16)(acc[mi][ni][rr] + bb);
        }
      }
    }
  } else {
    // V^T: [B,NH,DH,S]; 4 consecutive rows -> vector store
#pragma unroll
    for (int ni = 0; ni < 4; ++ni) {
      const int col = n0 + wn * 64 + ni * 16 + r;
      const int nh = col >> 6, dh = col & 63;
      const float bb = bias[col];
      bf16* orow = Out + ((size_t)b * NH + nh) * DH * S + (size_t)dh * S;
#pragma unroll
      for (int mi = 0; mi < 4; ++mi) {
        bf16x4 v;
#pragma unroll
        for (int rr = 0; rr < 4; ++rr) v[rr] = (bf16)(acc[mi][ni][rr] + bb);
        *reinterpret_cast<bf16x4*>(orow + m0 + wm * 64 + mi * 16 + lg * 4) = v;
      }
    }
  }
}

// ---------------- fused attention: LDS double-buffered K/V^T pipeline ----------------
// 1536 blocks (192 heads x 8 q-blocks of 64 rows), 256 threads = 4 waves.
__global__ __launch_bounds__(256, 4) void attn_kernel(
    const bf16* __restrict__ Qb, const bf16* __restrict__ Kb, const bf16* __restrict__ VTb,
    const float* __restrict__ mask, float* __restrict__ out)
{
  __shared__ __align__(16) bf16 Ks[2][64 * 64];
  __shared__ __align__(16) bf16 Vs[2][64 * 64];
  __shared__ float maskS[512];

  const int x = blockIdx.x;
  const int xcd = x & 7;
  const int grp = x >> 3;
  const int qblk = grp & 7;
  const int bh = (grp >> 3) * 8 + xcd;       // bijective over 1536 = 8*8*24
  const int b = bh / NH;
  const int h = bh % NH;
  const int tid = threadIdx.x;
  const int wave = tid >> 6;
  const int lane = tid & 63;
  const int r = lane & 15, lg = lane >> 4;
  const int q0 = qblk * 64 + wave * 16;

  const bf16* Q  = Qb  + (size_t)bh * S * DH;
  const bf16* K  = Kb  + (size_t)bh * S * DH;
  const bf16* VT = VTb + (size_t)bh * DH * S;   // [DH][S]

  for (int i = tid; i < S; i += 256) maskS[i] = mask[b * S + i];

  const int srowoff = lane >> 3;                 // 0..7
  const int sg = (lane & 7) ^ srowoff;           // pre-swizzled source chunk

  auto stage = [&](int kt, int buf) {
    const int kb = kt * 64;
#pragma unroll
    for (int i = 0; i < 2; ++i) {
      const int c = wave * 2 + i;                // 0..7
      const int row = c * 8 + srowoff;
      const bf16* gk = K + (size_t)(kb + row) * DH + sg * 8;
      __builtin_amdgcn_global_load_lds(
          (const __attribute__((address_space(1))) void*)gk,
          (__attribute__((address_space(3))) void*)(&Ks[buf][c * 512]), 16, 0, 0);
      const bf16* gv = VT + (size_t)row * S + kb + sg * 8;
      __builtin_amdgcn_global_load_lds(
          (const __attribute__((address_space(1))) void*)gv,
          (__attribute__((address_space(3))) void*)(&Vs[buf][c * 512]), 16, 0, 0);
    }
  };

  // hoisted Q fragments (this wave's 16 q-rows)
  const bf16x8 qf0 = *reinterpret_cast<const bf16x8*>(&Q[(size_t)(q0 + r) * DH + lg * 8]);
  const bf16x8 qf1 = *reinterpret_cast<const bf16x8*>(&Q[(size_t)(q0 + r) * DH + 32 + lg * 8]);

  stage(0, 0);
  __syncthreads();   // drains vmcnt(0)+lgkmcnt(0)

  float m = -3.0e38f, l = 0.0f;
  f32x4 ctx[4] = {};
  int buf = 0;

#pragma unroll 1
  for (int kt = 0; kt < 8; ++kt) {
    const int kb = kt * 64;
    if (kt < 7) stage(kt + 1, buf ^ 1);   // prefetch flies under this tile's compute

    // QK^T (swapped) from LDS: 4 k-subtiles of 16, K=64 in two MFMA steps
    f32x4 sa[4];
#pragma unroll
    for (int t = 0; t < 4; ++t) {
      const int row = t * 16 + r;
      const int sw = row & 7;
      bf16x8 kf0 = *reinterpret_cast<const bf16x8*>(&Ks[buf][row * 64 + ((lg ^ sw) * 8)]);
      bf16x8 kf1 = *reinterpret_cast<const bf16x8*>(&Ks[buf][row * 64 + (((lg + 4) ^ sw) * 8)]);
      f32x4 a = {};
      a = MFMA_16x16x32(kf0, qf0, a);
      a = MFMA_16x16x32(kf1, qf1, a);
      sa[t] = a;
    }

    // online softmax (lane's q = q0+r; k = kb + t*16 + lg*4 + rr)
    float tmax = -3.0e38f;
#pragma unroll
    for (int t = 0; t < 4; ++t)
#pragma unroll
      for (int rr = 0; rr < 4; ++rr) {
        float s = sa[t][rr] * 0.125f + maskS[kb + t * 16 + lg * 4 + rr];
        sa[t][rr] = s;
        tmax = fmaxf(tmax, s);
      }
    tmax = fmaxf(tmax, __shfl_xor(tmax, 16));
    tmax = fmaxf(tmax, __shfl_xor(tmax, 32));
    const float mnew = fmaxf(m, tmax);
    const float scale = __expf(m - mnew);
    m = mnew;
    float ps = 0.f;
#pragma unroll
    for (int t = 0; t < 4; ++t)
#pragma unroll
      for (int rr = 0; rr < 4; ++rr) {
        float p = __expf(sa[t][rr] - mnew);
        sa[t][rr] = p;
        ps += p;
      }
    l = l * scale + ps;
#pragma unroll
    for (int dt = 0; dt < 4; ++dt) ctx[dt] *= scale;

    // PV from LDS V^T tile: ctx^T[d][q] += V^T[d][k] * P^T[k][q]
#pragma unroll
    for (int kc = 0; kc < 2; ++kc) {
      bf16x8 pf;
      f32x4 p0 = sa[2 * kc], p1 = sa[2 * kc + 1];
      pf[0] = (bf16)p0[0]; pf[1] = (bf16)p0[1]; pf[2] = (bf16)p0[2]; pf[3] = (bf16)p0[3];
      pf[4] = (bf16)p1[0]; pf[5] = (bf16)p1[1]; pf[6] = (bf16)p1[2]; pf[7] = (bf16)p1[3];
      const int chunk_lo = kc * 4 + (lg >> 1);
      const int rem = (lg & 1) * 4;              // elements
#pragma unroll
      for (int dt = 0; dt < 4; ++dt) {
        const int row = dt * 16 + r;
        const int sw = row & 7;
        const bf16* vlo = &Vs[buf][row * 64 + ((chunk_lo ^ sw) * 8) + rem];
        const bf16* vhi = &Vs[buf][row * 64 + (((chunk_lo + 2) ^ sw) * 8) + rem];
        bf16x4 lo = *reinterpret_cast<const bf16x4*>(vlo);
        bf16x4 hi = *reinterpret_cast<const bf16x4*>(vhi);
        bf16x8 vf;
        vf[0] = lo[0]; vf[1] = lo[1]; vf[2] = lo[2]; vf[3] = lo[3];
        vf[4] = hi[0]; vf[5] = hi[1]; vf[6] = hi[2]; vf[7] = hi[3];
        ctx[dt] = MFMA_16x16x32(vf, pf, ctx[dt]);
      }
    }

    __syncthreads();   // drains vmcnt (next tile staged) + all waves done with buf
    buf ^= 1;
  }

  l += __shfl_xor(l, 16);
  l += __shfl_xor(l, 32);
  const float inv = 1.0f / l;

  // write ctx (f32, vectorized): lane's q = q0+r, d = dt*16 + lg*4 + rr
  float* obase = out + ((size_t)b * S + q0 + r) * H + h * DH;
#pragma unroll
  for (int dt = 0; dt < 4; ++dt) {
    float4 o;
    o.x = ctx[dt][0] * inv; o.y = ctx[dt][1] * inv;
    o.z = ctx[dt][2] * inv; o.w = ctx[dt][3] * inv;
    *reinterpret_cast<float4*>(obase + dt * 16 + lg * 4) = o;
  }
}

extern "C" void kernel_launch(void* const* d_in, const int* in_sizes, int n_in,
                              void* d_out, int out_size, void* d_ws, size_t ws_size,
                              hipStream_t stream) {
  const float* hidden = (const float*)d_in[0];
  const float* mask   = (const float*)d_in[1];
  const float* Wq = (const float*)d_in[2];
  const float* bq = (const float*)d_in[3];
  const float* Wk = (const float*)d_in[4];
  const float* bk = (const float*)d_in[5];
  const float* Wv = (const float*)d_in[6];
  const float* bv = (const float*)d_in[7];
  const int* eidx = (const int*)d_in[8];

  if (ws_size < WS_NEED) return;

  char* ws = (char*)d_ws;
  bf16* Xb  = (bf16*)(ws + XB_OFF);
  bf16* Qbf = (bf16*)(ws + QB_OFF);
  bf16* Kbf = (bf16*)(ws + KB_OFF);
  bf16* Vbf = (bf16*)(ws + VB_OFF);
  float* out = (float*)d_out;

  cvt_x<<<3072, 256, 0, stream>>>(hidden, Xb);
  proj_gemm<<<576, 512, 0, stream>>>(Xb, Wq, Wk, Wv, bq, bk, bv, eidx,
                                     Qbf, Kbf, Vbf);
  attn_kernel<<<1536, 256, 0, stream>>>(Qbf, Kbf, Vbf, mask, out);
}

// Round 12
// 101.704 us; speedup vs baseline: 1.2424x; 1.2424x over previous
//
#include <hip/hip_runtime.h>
#include <hip/hip_bf16.h>
#include <stdint.h>

typedef __bf16 bf16;
typedef bf16 bf16x8 __attribute__((ext_vector_type(8)));
typedef bf16 bf16x4 __attribute__((ext_vector_type(4)));
typedef float f32x4 __attribute__((ext_vector_type(4)));

#define MFMA_16x16x32(a, b, c) __builtin_amdgcn_mfma_f32_16x16x32_bf16((a), (b), (c), 0, 0, 0)

// ---- problem sizes ----
constexpr int B = 16, S = 512, H = 768, NH = 12, DH = 64;
constexpr long NHID = (long)B * S * H;          // 6291456

// ---- workspace layout (bytes) ----
constexpr size_t XB_OFF = 0;
constexpr size_t XB_SZ  = (size_t)NHID * 2;
constexpr size_t PROJ_SZ = (size_t)B * NH * S * DH * 2;  // 12582912
constexpr size_t QB_OFF = XB_OFF + XB_SZ;
constexpr size_t KB_OFF = QB_OFF + PROJ_SZ;
constexpr size_t VB_OFF = KB_OFF + PROJ_SZ;              // V^T: [B,NH,DH,S]
constexpr size_t WS_NEED = VB_OFF + PROJ_SZ;             // ~50 MB

// ---------------- X-only f32 -> bf16 convert ----------------
__global__ void cvt_x(const float* __restrict__ src, bf16* __restrict__ dst) {
  long i = ((long)blockIdx.x * blockDim.x + threadIdx.x) * 8;
  if (i >= NHID) return;
  const float4* sp = reinterpret_cast<const float4*>(src + i);
  float4 a = sp[0], b = sp[1];
  bf16x8 o;
  o[0] = (bf16)a.x; o[1] = (bf16)a.y; o[2] = (bf16)a.z; o[3] = (bf16)a.w;
  o[4] = (bf16)b.x; o[5] = (bf16)b.y; o[6] = (bf16)b.z; o[7] = (bf16)b.w;
  *reinterpret_cast<bf16x8*>(dst + i) = o;
}

// ---------------- projection GEMM (R7 structure; W converted in-reg) ----------------
// 576 blocks = 8 XCD-groups x (2 batches x 2 m-tiles x 18 n-tiles), 512 thr.
// BM=256, BN=128, BK=32, dbuf 48KB -> 2 blocks/CU, 16 waves/CU.
// A = X bf16 via global_load_lds (R7-verified swizzle, 0-conflict).
// B = W f32 loaded to REGISTERS (2x dwordx4/thread), cvt in-reg, one
//     ds_write_b128 into the SAME bf16 layout R7 reads (slot q^((row>>1)&3)).
//     T14: loads issue at top of iter (pinned by sched_barrier), write after MFMA.
// Q,K written [B,NH,S,DH]; V written TRANSPOSED [B,NH,DH,S].
__global__ __launch_bounds__(512, 2) void proj_gemm(
    const bf16* __restrict__ Xb,
    const float* __restrict__ Wqf, const float* __restrict__ Wkf, const float* __restrict__ Wvf,
    const float* __restrict__ bq, const float* __restrict__ bk, const float* __restrict__ bv,
    const int* __restrict__ eidx,
    bf16* __restrict__ Qb, bf16* __restrict__ Kb, bf16* __restrict__ Vb)
{
  __shared__ __align__(16) bf16 As[2][256 * 32];   // 32 KB
  __shared__ __align__(16) bf16 Bs[2][128 * 32];   // 16 KB

  // XCD-grouped decode: xcd = blk&7 owns batches {2*xcd, 2*xcd+1}
  const int xcd = blockIdx.x & 7;
  const int bi  = blockIdx.x >> 3;            // 0..71
  const int b   = xcd * 2 + (bi / 36);        // batch
  const int rem = bi % 36;                    // 2 m-tiles x 18 n-tiles
  const int m0  = (rem / 18) * 256;
  const int gy  = rem % 18;
  const int proj = gy / 6;
  const int n0 = (gy % 6) * 128;
  const int e = eidx[b];

  const float* W = (proj == 0 ? Wqf : (proj == 1 ? Wkf : Wvf)) + (size_t)e * H * H;
  const float* bias = (proj == 0 ? bq : (proj == 1 ? bk : bv)) + (size_t)e * H;
  bf16* Out = (proj == 0 ? Qb : (proj == 1 ? Kb : Vb));

  const int tid = threadIdx.x;
  const int lane = tid & 63;
  const int wave = tid >> 6;                  // 0..7
  const int wm = wave >> 1, wn = wave & 1;    // 4 x 64 m, 2 x 64 n
  const int r = lane & 15, lg = lane >> 4;

  const bf16* Abase = Xb + ((size_t)b * S + m0) * H;

  // A staging (R7-verified): unit = 16 rows x 32 bf16; 2 units/wave.
  const int srowA = lane >> 2;                           // 0..15
  const int sgA = ((lane & 3) ^ ((lane >> 3) & 3)) * 8;  // bf16 elems

  auto stageA = [&](int kt, int pb) {
    const int k0 = kt * 32;
#pragma unroll
    for (int i = 0; i < 2; ++i) {
      const int seg = wave * 2 + i;                      // 0..15
      const bf16* ga = Abase + (size_t)(seg * 16 + srowA) * H + k0 + sgA;
      __builtin_amdgcn_global_load_lds(
          (const __attribute__((address_space(1))) void*)ga,
          (__attribute__((address_space(3))) void*)(&As[pb][seg * 512]), 16, 0, 0);
    }
  };

  // B reg-staging: thread covers row=tid>>2 (0..127), chunk q=tid&3 (8 f32).
  const int rowB = tid >> 2;
  const int qB = tid & 3;
  const int slotB = (qB ^ ((rowB >> 1) & 3)) * 8;        // matches R7 read swizzle
  const float* gB = W + (size_t)(n0 + rowB) * H + qB * 8;

  f32x4 lb0, lb1;
  auto loadB = [&](int kt) {
    const float* p = gB + kt * 32;
    lb0 = *reinterpret_cast<const f32x4*>(p);
    lb1 = *reinterpret_cast<const f32x4*>(p + 4);
  };
  auto writeB = [&](int pb) {
    bf16x8 o;
    o[0] = (bf16)lb0[0]; o[1] = (bf16)lb0[1]; o[2] = (bf16)lb0[2]; o[3] = (bf16)lb0[3];
    o[4] = (bf16)lb1[0]; o[5] = (bf16)lb1[1]; o[6] = (bf16)lb1[2]; o[7] = (bf16)lb1[3];
    *reinterpret_cast<bf16x8*>(&Bs[pb][rowB * 32 + slotB]) = o;
  };

  f32x4 acc[4][4] = {};

  stageA(0, 0);
  loadB(0);
  writeB(0);            // compiler inserts vmcnt wait for lb regs
  __syncthreads();      // drains A gloads + B ds_write

  const int sz = (r >> 1) & 3;   // read-side swizzle index

  int buf = 0;
#pragma unroll 1
  for (int kt = 0; kt < 24; ++kt) {
    if (kt < 23) {
      stageA(kt + 1, buf ^ 1);   // DMA prefetch
      loadB(kt + 1);             // reg prefetch (W f32)
    }
    __builtin_amdgcn_sched_barrier(0);   // pin load issue above compute

    bf16x8 af[4], bfr[4];
#pragma unroll
    for (int mi = 0; mi < 4; ++mi)
      af[mi] = *reinterpret_cast<const bf16x8*>(
          &As[buf][(wm * 64 + mi * 16 + r) * 32 + ((lg ^ sz) * 8)]);
#pragma unroll
    for (int ni = 0; ni < 4; ++ni)
      bfr[ni] = *reinterpret_cast<const bf16x8*>(
          &Bs[buf][(wn * 64 + ni * 16 + r) * 32 + ((lg ^ sz) * 8)]);
    __builtin_amdgcn_s_setprio(1);
#pragma unroll
    for (int mi = 0; mi < 4; ++mi)
#pragma unroll
      for (int ni = 0; ni < 4; ++ni)
        acc[mi][ni] = MFMA_16x16x32(af[mi], bfr[ni], acc[mi][ni]);
    __builtin_amdgcn_s_setprio(0);

    if (kt < 23) writeB(buf ^ 1);   // T14 write-late: cvt + ds_write

    __syncthreads();   // next tile (A DMA + B write) resolved; all waves off buf
    buf ^= 1;
  }

  // epilogue: bias add, cast bf16
  if (proj != 2) {
    // Q,K: [B,NH,S,DH] scatter
#pragma unroll
    for (int ni = 0; ni < 4; ++ni) {
      const int col = n0 + wn * 64 + ni * 16 + r;
      const int nh = col >> 6, dh = col & 63;
      const float bb = bias[col];
      bf16* orow = Out + ((size_t)b * NH + nh) * S * DH + dh;
#pragma unroll
      for (int mi = 0; mi < 4; ++mi) {
#pragma unroll
        for (int rr = 0; rr < 4; ++rr) {
          const int srow2 = m0 + wm * 64 + mi * 16 + lg * 4 + rr;
          orow[(size_t)srow2 * DH] = (bf16)(acc[mi][ni][rr] + bb);
        }
      }
    }
  } else {
    // V^T: [B,NH,DH,S]; 4 consecutive rows -> vector store
#pragma unroll
    for (int ni = 0; ni < 4; ++ni) {
      const int col = n0 + wn * 64 + ni * 16 + r;
      const int nh = col >> 6, dh = col & 63;
      const float bb = bias[col];
      bf16* orow = Out + ((size_t)b * NH + nh) * DH * S + (size_t)dh * S;
#pragma unroll
      for (int mi = 0; mi < 4; ++mi) {
        bf16x4 v;
#pragma unroll
        for (int rr = 0; rr < 4; ++rr) v[rr] = (bf16)(acc[mi][ni][rr] + bb);
        *reinterpret_cast<bf16x4*>(orow + m0 + wm * 64 + mi * 16 + lg * 4) = v;
      }
    }
  }
}

// ---------------- fused attention: LDS double-buffered K/V^T pipeline ----------------
// 1536 blocks (192 heads x 8 q-blocks of 64 rows), 256 threads = 4 waves.
__global__ __launch_bounds__(256, 4) void attn_kernel(
    const bf16* __restrict__ Qb, const bf16* __restrict__ Kb, const bf16* __restrict__ VTb,
    const float* __restrict__ mask, float* __restrict__ out)
{
  __shared__ __align__(16) bf16 Ks[2][64 * 64];
  __shared__ __align__(16) bf16 Vs[2][64 * 64];
  __shared__ float maskS[512];

  const int x = blockIdx.x;
  const int xcd = x & 7;
  const int grp = x >> 3;
  const int qblk = grp & 7;
  const int bh = (grp >> 3) * 8 + xcd;       // bijective over 1536 = 8*8*24
  const int b = bh / NH;
  const int h = bh % NH;
  const int tid = threadIdx.x;
  const int wave = tid >> 6;
  const int lane = tid & 63;
  const int r = lane & 15, lg = lane >> 4;
  const int q0 = qblk * 64 + wave * 16;

  const bf16* Q  = Qb  + (size_t)bh * S * DH;
  const bf16* K  = Kb  + (size_t)bh * S * DH;
  const bf16* VT = VTb + (size_t)bh * DH * S;   // [DH][S]

  for (int i = tid; i < S; i += 256) maskS[i] = mask[b * S + i];

  const int srowoff = lane >> 3;                 // 0..7
  const int sg = (lane & 7) ^ srowoff;           // pre-swizzled source chunk

  auto stage = [&](int kt, int buf) {
    const int kb = kt * 64;
#pragma unroll
    for (int i = 0; i < 2; ++i) {
      const int c = wave * 2 + i;                // 0..7
      const int row = c * 8 + srowoff;
      const bf16* gk = K + (size_t)(kb + row) * DH + sg * 8;
      __builtin_amdgcn_global_load_lds(
          (const __attribute__((address_space(1))) void*)gk,
          (__attribute__((address_space(3))) void*)(&Ks[buf][c * 512]), 16, 0, 0);
      const bf16* gv = VT + (size_t)row * S + kb + sg * 8;
      __builtin_amdgcn_global_load_lds(
          (const __attribute__((address_space(1))) void*)gv,
          (__attribute__((address_space(3))) void*)(&Vs[buf][c * 512]), 16, 0, 0);
    }
  };

  // hoisted Q fragments (this wave's 16 q-rows)
  const bf16x8 qf0 = *reinterpret_cast<const bf16x8*>(&Q[(size_t)(q0 + r) * DH + lg * 8]);
  const bf16x8 qf1 = *reinterpret_cast<const bf16x8*>(&Q[(size_t)(q0 + r) * DH + 32 + lg * 8]);

  stage(0, 0);
  __syncthreads();   // drains vmcnt(0)+lgkmcnt(0)

  float m = -3.0e38f, l = 0.0f;
  f32x4 ctx[4] = {};
  int buf = 0;

#pragma unroll 1
  for (int kt = 0; kt < 8; ++kt) {
    const int kb = kt * 64;
    if (kt < 7) stage(kt + 1, buf ^ 1);   // prefetch flies under this tile's compute

    // QK^T (swapped) from LDS: 4 k-subtiles of 16, K=64 in two MFMA steps
    f32x4 sa[4];
#pragma unroll
    for (int t = 0; t < 4; ++t) {
      const int row = t * 16 + r;
      const int sw = row & 7;
      bf16x8 kf0 = *reinterpret_cast<const bf16x8*>(&Ks[buf][row * 64 + ((lg ^ sw) * 8)]);
      bf16x8 kf1 = *reinterpret_cast<const bf16x8*>(&Ks[buf][row * 64 + (((lg + 4) ^ sw) * 8)]);
      f32x4 a = {};
      a = MFMA_16x16x32(kf0, qf0, a);
      a = MFMA_16x16x32(kf1, qf1, a);
      sa[t] = a;
    }

    // online softmax (lane's q = q0+r; k = kb + t*16 + lg*4 + rr)
    float tmax = -3.0e38f;
#pragma unroll
    for (int t = 0; t < 4; ++t)
#pragma unroll
      for (int rr = 0; rr < 4; ++rr) {
        float s = sa[t][rr] * 0.125f + maskS[kb + t * 16 + lg * 4 + rr];
        sa[t][rr] = s;
        tmax = fmaxf(tmax, s);
      }
    tmax = fmaxf(tmax, __shfl_xor(tmax, 16));
    tmax = fmaxf(tmax, __shfl_xor(tmax, 32));
    const float mnew = fmaxf(m, tmax);
    const float scale = __expf(m - mnew);
    m = mnew;
    float ps = 0.f;
#pragma unroll
    for (int t = 0; t < 4; ++t)
#pragma unroll
      for (int rr = 0; rr < 4; ++rr) {
        float p = __expf(sa[t][rr] - mnew);
        sa[t][rr] = p;
        ps += p;
      }
    l = l * scale + ps;
#pragma unroll
    for (int dt = 0; dt < 4; ++dt) ctx[dt] *= scale;

    // PV from LDS V^T tile: ctx^T[d][q] += V^T[d][k] * P^T[k][q]
#pragma unroll
    for (int kc = 0; kc < 2; ++kc) {
      bf16x8 pf;
      f32x4 p0 = sa[2 * kc], p1 = sa[2 * kc + 1];
      pf[0] = (bf16)p0[0]; pf[1] = (bf16)p0[1]; pf[2] = (bf16)p0[2]; pf[3] = (bf16)p0[3];
      pf[4] = (bf16)p1[0]; pf[5] = (bf16)p1[1]; pf[6] = (bf16)p1[2]; pf[7] = (bf16)p1[3];
      const int chunk_lo = kc * 4 + (lg >> 1);
      const int rem = (lg & 1) * 4;              // elements
#pragma unroll
      for (int dt = 0; dt < 4; ++dt) {
        const int row = dt * 16 + r;
        const int sw = row & 7;
        const bf16* vlo = &Vs[buf][row * 64 + ((chunk_lo ^ sw) * 8) + rem];
        const bf16* vhi = &Vs[buf][row * 64 + (((chunk_lo + 2) ^ sw) * 8) + rem];
        bf16x4 lo = *reinterpret_cast<const bf16x4*>(vlo);
        bf16x4 hi = *reinterpret_cast<const bf16x4*>(vhi);
        bf16x8 vf;
        vf[0] = lo[0]; vf[1] = lo[1]; vf[2] = lo[2]; vf[3] = lo[3];
        vf[4] = hi[0]; vf[5] = hi[1]; vf[6] = hi[2]; vf[7] = hi[3];
        ctx[dt] = MFMA_16x16x32(vf, pf, ctx[dt]);
      }
    }

    __syncthreads();   // drains vmcnt (next tile staged) + all waves done with buf
    buf ^= 1;
  }

  l += __shfl_xor(l, 16);
  l += __shfl_xor(l, 32);
  const float inv = 1.0f / l;

  // write ctx (f32, vectorized): lane's q = q0+r, d = dt*16 + lg*4 + rr
  float* obase = out + ((size_t)b * S + q0 + r) * H + h * DH;
#pragma unroll
  for (int dt = 0; dt < 4; ++dt) {
    float4 o;
    o.x = ctx[dt][0] * inv; o.y = ctx[dt][1] * inv;
    o.z = ctx[dt][2] * inv; o.w = ctx[dt][3] * inv;
    *reinterpret_cast<float4*>(obase + dt * 16 + lg * 4) = o;
  }
}

extern "C" void kernel_launch(void* const* d_in, const int* in_sizes, int n_in,
                              void* d_out, int out_size, void* d_ws, size_t ws_size,
                              hipStream_t stream) {
  const float* hidden = (const float*)d_in[0];
  const float* mask   = (const float*)d_in[1];
  const float* Wq = (const float*)d_in[2];
  const float* bq = (const float*)d_in[3];
  const float* Wk = (const float*)d_in[4];
  const float* bk = (const float*)d_in[5];
  const float* Wv = (const float*)d_in[6];
  const float* bv = (const float*)d_in[7];
  const int* eidx = (const int*)d_in[8];

  if (ws_size < WS_NEED) return;

  char* ws = (char*)d_ws;
  bf16* Xb  = (bf16*)(ws + XB_OFF);
  bf16* Qbf = (bf16*)(ws + QB_OFF);
  bf16* Kbf = (bf16*)(ws + KB_OFF);
  bf16* Vbf = (bf16*)(ws + VB_OFF);
  float* out = (float*)d_out;

  cvt_x<<<3072, 256, 0, stream>>>(hidden, Xb);
  proj_gemm<<<576, 512, 0, stream>>>(Xb, Wq, Wk, Wv, bq, bk, bv, eidx,
                                     Qbf, Kbf, Vbf);
  attn_kernel<<<1536, 256, 0, stream>>>(Qbf, Kbf, Vbf, mask, out);
}